// Round 7
// baseline (242.588 us; speedup 1.0000x reference)
//
#include <hip/hip_runtime.h>
#include <stdint.h>

// BinaryLinearWscales: out[m,n] = wscale[n] * (x @ sign(W)^T)[m,n] + wbias[n] * rowsum(x)[m]
// M = B*S = 4096, N = DOUT = 4096, K = DIN = 4096.
// Round 12: merged phases — 2 per K-tile (was 4). Evidence: per-phase fixed
//   overhead θ ~300-700 cy (phase time 1350-1444 invariant across r7/r8/r9
//   structures; additive LDS+MFMA+θ). Halving phase count halves the θ bill.
//   Merged phase = one K-half: 12 ds_read + 16 MFMA / wave + A&B half-tile
//   stage (4 loads/thread). Uniform ENDSYNC = vmcnt(4)+s_barrier. Read-ahead
//   register pipeline kept (lgkmcnt(12)). VGPR diet: frag addressing = 4 base
//   regs + ds_read immediates (sw=(col32>>1)&3 is mi/nj-independent); staging
//   = uniform SGPR bases + 2 shared 32-bit offsets.
//   prep: UNCHANGED from round 11 (isolate the gemm delta).

#define MDIM 4096
#define NDIM 4096
#define KDIM 4096

typedef int int4v  __attribute__((ext_vector_type(4)));
typedef int int16v __attribute__((ext_vector_type(16)));

__device__ __forceinline__ int pack4_rn(float a, float b, float c, float d, float inv) {
  int ia = __float2int_rn(a * inv) & 0xff;
  int ib = __float2int_rn(b * inv) & 0xff;
  int ic = __float2int_rn(c * inv) & 0xff;
  int id = __float2int_rn(d * inv) & 0xff;
  return ia | (ib << 8) | (ic << 16) | (id << 24);
}

__device__ __forceinline__ int sgn8(float v) {
  return (v > 0.f) ? 1 : ((v < 0.f) ? 0xff : 0);
}

// ---------------- prep (UNCHANGED from round 11) ----------------
#define PREP_XB 1024
#define PREP_WB 1024
__global__ __launch_bounds__(256) void prep_kernel(
    const float* __restrict__ x, const float* __restrict__ w,
    char* __restrict__ xq, char* __restrict__ wsg,
    float* __restrict__ xscale, float* __restrict__ sumx) {
  const int b = blockIdx.x;
  const int tid = threadIdx.x;
  const int lane = tid & 63, wv = tid >> 6;
  if (b < PREP_XB) {
    const int row = b * 4 + wv;
    const float4* xr = (const float4*)(x + (size_t)row * KDIM);
    float4 v[16];
    float s = 0.f, amax = 0.f;
#pragma unroll
    for (int u = 0; u < 16; ++u) {
      v[u] = xr[u * 64 + lane];
      s += v[u].x + v[u].y + v[u].z + v[u].w;
      amax = fmaxf(amax, fmaxf(fmaxf(fabsf(v[u].x), fabsf(v[u].y)),
                               fmaxf(fabsf(v[u].z), fabsf(v[u].w))));
    }
#pragma unroll
    for (int off = 32; off > 0; off >>= 1) {
      s += __shfl_xor(s, off, 64);
      amax = fmaxf(amax, __shfl_xor(amax, off, 64));
    }
    if (lane == 0) {
      sumx[row] = s;
      xscale[row] = amax * (1.f / 127.f);
    }
    const float inv = (amax > 0.f) ? 127.f / amax : 0.f;
    int* xo = (int*)(xq + (size_t)row * KDIM);
#pragma unroll
    for (int u = 0; u < 16; ++u)
      xo[u * 64 + lane] = pack4_rn(v[u].x, v[u].y, v[u].z, v[u].w, inv);
  } else {
    const float4* wr = (const float4*)w;
    int* wo = (int*)wsg;
    const size_t i0 = (size_t)(b - PREP_XB) * 256 + tid;
    const size_t stride = (size_t)PREP_WB * 256;
#pragma unroll
    for (int u = 0; u < 16; ++u) {
      size_t i = i0 + (size_t)u * stride;
      float4 vv = wr[i];
      wo[i] = sgn8(vv.x) | (sgn8(vv.y) << 8) | (sgn8(vv.z) << 16) | (sgn8(vv.w) << 24);
    }
  }
}

// ---------------- 256x256 merged-phase i8 GEMM (32x32x32 MFMA) ----------------
__global__ __launch_bounds__(512, 2) void gemm_bin_i8_m2(
    const char* __restrict__ A, const char* __restrict__ Bs,
    const float* __restrict__ wscale, const float* __restrict__ wbias,
    const float* __restrict__ xscale, const float* __restrict__ sumx,
    float* __restrict__ C) {
  // A slots: [0,64K) = (buf*2+kh)*16384 ; B slots: [64K,128K) = 65536 + same
  __shared__ __align__(16) char sm[131072];

  const int bm = blockIdx.x >> 4, bn = blockIdx.x & 15;
  const int tm0 = bm * 256, tn0 = bn * 256;
  const int tid = threadIdx.x;
  const int lane = tid & 63, wave = tid >> 6;
  const int col32 = lane & 31, hl = lane >> 5;
  const int wr = wave >> 2, wc = wave & 3;   // 2 x 4 wave grid, wave tile 128x64

  int16v acc[4][2];
#pragma unroll
  for (int mi = 0; mi < 4; ++mi)
#pragma unroll
    for (int nj = 0; nj < 2; ++nj)
#pragma unroll
      for (int r = 0; r < 16; ++r) acc[mi][nj][r] = 0;

  // two static fragment register sets: 12 frags each (af[ks2*4+mi], bq[ks2*2+nj])
  int4v afA[8], bqA[4], afB[8], bqB[4];

  // fragment base addrs: sw = (row>>1)&3 depends only on col32 bits [2:1]
  // aOff[ks2][mi] = baseA[ks2] + mi*2048 ; bOff[ks2][nj] = 65536 + baseB[ks2] + nj*2048
  const int swc = (col32 >> 1) & 3;
  int baseA[2], baseB[2];
#pragma unroll
  for (int ks2 = 0; ks2 < 2; ++ks2) {
    baseA[ks2] = (wr * 128 + col32) * 64 + (((ks2 * 2 + hl) ^ swc) & 3) * 16;
    baseB[ks2] = (wc * 64 + col32) * 64 + (((ks2 * 2 + hl) ^ swc) & 3) * 16;
  }

  // staging: half-tile = 256 rows x 64B = 16KB = 2 rounds of 512 thr x 16B.
  // linear LDS dest u*16 <- global logical chunk (u&3)^sw(row); A/B share offsets.
  const int u0 = tid, u1 = tid + 512;
  const int r0 = u0 >> 2, r1 = u1 >> 2;
  const int c0 = (u0 & 3) ^ ((r0 >> 1) & 3);
  const int c1 = (u1 & 3) ^ ((r1 >> 1) & 3);
  const int offs0 = r0 * KDIM + c0 * 16;
  const int offs1 = r1 * KDIM + c1 * 16;
  const char* Abase = A + (size_t)tm0 * KDIM;    // wave-uniform -> SGPR
  const char* Bbase = Bs + (size_t)tn0 * KDIM;
  const int ldsu0 = tid * 16, ldsu1 = 8192 + tid * 16;

#define STAGE_AB(BUF, KH, KOFS)                                                   \
  do {                                                                            \
    const int sa_ = ((BUF) * 2 + (KH)) * 16384;                                   \
    const int sb_ = 65536 + sa_;                                                  \
    __builtin_amdgcn_global_load_lds(                                             \
        (const __attribute__((address_space(1))) void*)(Abase + offs0 + (KOFS)),  \
        (__attribute__((address_space(3))) void*)(sm + sa_ + ldsu0), 16, 0, 0);   \
    __builtin_amdgcn_global_load_lds(                                             \
        (const __attribute__((address_space(1))) void*)(Abase + offs1 + (KOFS)),  \
        (__attribute__((address_space(3))) void*)(sm + sa_ + ldsu1), 16, 0, 0);   \
    __builtin_amdgcn_global_load_lds(                                             \
        (const __attribute__((address_space(1))) void*)(Bbase + offs0 + (KOFS)),  \
        (__attribute__((address_space(3))) void*)(sm + sb_ + ldsu0), 16, 0, 0);   \
    __builtin_amdgcn_global_load_lds(                                             \
        (const __attribute__((address_space(1))) void*)(Bbase + offs1 + (KOFS)),  \
        (__attribute__((address_space(3))) void*)(sm + sb_ + ldsu1), 16, 0, 0);   \
  } while (0)

// 12 fragment reads (next phase's operands) into regset SET from slot (BUF,KS)
#define DSRD(SET, BUF, KS)                                                        \
  do {                                                                            \
    const int sa_ = ((BUF) * 2 + (KS)) * 16384;                                   \
    const int sb_ = 65536 + sa_;                                                  \
    _Pragma("unroll") for (int k2_ = 0; k2_ < 2; ++k2_) {                         \
      _Pragma("unroll") for (int mi_ = 0; mi_ < 4; ++mi_)                         \
          af##SET[k2_ * 4 + mi_] =                                                \
              *(const int4v*)(sm + sa_ + baseA[k2_] + mi_ * 2048);                \
      _Pragma("unroll") for (int nj_ = 0; nj_ < 2; ++nj_)                         \
          bq##SET[k2_ * 2 + nj_] =                                                \
              *(const int4v*)(sm + sb_ + baseB[k2_] + nj_ * 2048);                \
    }                                                                             \
  } while (0)

#define MFMA16(SET)                                                               \
  do {                                                                            \
    __builtin_amdgcn_s_setprio(1);                                                \
    _Pragma("unroll") for (int k2_ = 0; k2_ < 2; ++k2_)                           \
        _Pragma("unroll") for (int mi_ = 0; mi_ < 4; ++mi_)                       \
            _Pragma("unroll") for (int nj_ = 0; nj_ < 2; ++nj_)                   \
                acc[mi_][nj_] = __builtin_amdgcn_mfma_i32_32x32x32_i8(            \
                    af##SET[k2_ * 4 + mi_], bq##SET[k2_ * 2 + nj_],               \
                    acc[mi_][nj_], 0, 0, 0);                                      \
    __builtin_amdgcn_s_setprio(0);                                                \
  } while (0)

// wait own 12 frags; the 12 just-issued (next phase) stay outstanding
#define WAITL12                                                                   \
  do {                                                                            \
    asm volatile("s_waitcnt lgkmcnt(12)" ::: "memory");                           \
    __builtin_amdgcn_sched_barrier(0);                                            \
  } while (0)
#define WAITL0                                                                    \
  do {                                                                            \
    asm volatile("s_waitcnt lgkmcnt(0)" ::: "memory");                            \
    __builtin_amdgcn_sched_barrier(0);                                            \
  } while (0)

#define CKV4 asm volatile("s_waitcnt vmcnt(4)\n\ts_barrier" ::: "memory")
#define CKV0 asm volatile("s_waitcnt vmcnt(0)\n\ts_barrier" ::: "memory")

// phase: {12 ds_read -> NSET ; stage A+B half-tile} || {wait own ; 16 MFMA CSET} ; ENDSYNC
#define PHASE(CSET, NSET, NBUF, NKS, STAGEOP, ENDSYNC)                            \
  do {                                                                            \
    DSRD(NSET, NBUF, NKS);                                                        \
    STAGEOP;                                                                      \
    WAITL12;                                                                      \
    MFMA16(CSET);                                                                 \
    ENDSYNC;                                                                      \
  } while (0)

// one K-tile (2 merged phases), tile TAU in buf BUF:
//   P0: compute (BUF,k0) [set A], read-ahead (BUF,k1), stage (TAU+1) k1
//   P1: compute (BUF,k1) [set B], read-ahead (BUF^1,k0) = (TAU+1) k0, stage (TAU+2) k0
// uniform ENDSYNC vmcnt(4): drains the group staged 2 phases ago (the one the
// NEXT phase reads ahead), keeps the newest group in flight (~1.5 phases ~3000cy).
#define TILE_MAIN(BUF, TAU)                                                       \
  do {                                                                            \
    PHASE(A, B, BUF, 1, STAGE_AB((BUF) ^ 1, 1, ((TAU) + 1) * 128 + 64), CKV4);    \
    PHASE(B, A, (BUF) ^ 1, 0, STAGE_AB(BUF, 0, ((TAU) + 2) * 128), CKV4);         \
  } while (0)

  // prologue: stage tile0{k0,k1} + tile1{k0}; vmcnt(4) drains tile0 (keeps
  // tile1-k0 in flight = steady-entry invariant); pre-read (0,k0).
  STAGE_AB(0, 0, 0);
  STAGE_AB(0, 1, 64);
  STAGE_AB(1, 0, 128);
  CKV4;
  DSRD(A, 0, 0);

  // tiles 0..29
#pragma unroll 1
  for (int t = 0; t < 30; t += 2) {
    TILE_MAIN(0, t);
    TILE_MAIN(1, t + 1);
  }

  // tile 30 (buf 0): P0 normal (stages (31,k1)); P1 stages nothing, drains all
  PHASE(A, B, 0, 1, STAGE_AB(1, 1, 31 * 128 + 64), CKV4);
  PHASE(B, A, 1, 0, (void)0, CKV0);
  // tile 31 (buf 1): compute only
  PHASE(A, B, 1, 1, (void)0, (void)0);
  WAITL0;
  MFMA16(B);

#undef TILE_MAIN
#undef PHASE
#undef CKV4
#undef CKV0
#undef WAITL12
#undef WAITL0
#undef MFMA16
#undef DSRD
#undef STAGE_AB

  // epilogue: C[m,n] = wscale[n]*xscale[m]*acc + wbias[n]*sumx[m]
  // 32x32 C/D layout (m74/m101): col = lane&31, row = (reg&3)+8*(reg>>2)+4*hl
  float wsv[2], wbv[2];
#pragma unroll
  for (int nj = 0; nj < 2; ++nj) {
    int n = tn0 + wc * 64 + nj * 32 + col32;
    wsv[nj] = wscale[n];
    wbv[nj] = wbias[n];
  }
#pragma unroll
  for (int mi = 0; mi < 4; ++mi) {
#pragma unroll
    for (int reg = 0; reg < 16; ++reg) {
      int m = tm0 + wr * 128 + mi * 32 + (reg & 3) + 8 * (reg >> 2) + 4 * hl;
      float xs = xscale[m];
      float sx = sumx[m];
      float* crow = C + (size_t)m * NDIM + tn0 + wc * 64 + col32;
#pragma unroll
      for (int nj = 0; nj < 2; ++nj)
        crow[nj * 32] = wsv[nj] * xs * (float)acc[mi][nj][reg] + wbv[nj] * sx;
    }
  }
}

extern "C" void kernel_launch(void* const* d_in, const int* in_sizes, int n_in,
                              void* d_out, int out_size, void* d_ws, size_t ws_size,
                              hipStream_t stream) {
  const float* x      = (const float*)d_in[0];
  const float* weight = (const float*)d_in[1];
  const float* wscale = (const float*)d_in[2];
  const float* wbias  = (const float*)d_in[3];
  float* out = (float*)d_out;

  char* xq  = (char*)d_ws;
  char* wsg = xq + (size_t)MDIM * KDIM;
  float* xscale = (float*)(wsg + (size_t)NDIM * KDIM);
  float* sumx   = xscale + MDIM;

  prep_kernel<<<PREP_XB + PREP_WB, 256, 0, stream>>>(
      x, weight, xq, wsg, xscale, sumx);
  gemm_bin_i8_m2<<<(MDIM / 256) * (NDIM / 256), 512, 0, stream>>>(
      xq, wsg, wscale, wbias, xscale, sumx, out);
}